// Round 8
// baseline (80.241 us; speedup 1.0000x reference)
//
#include <hip/hip_runtime.h>

#define EPSF 1e-8f
#define PROB_PENALTYF 1e-4f
#define REV_SCALEF 0.1f
#define INFBITS 0x7F800000u
#define ONEBF ((unsigned short)0x3F80)   // bf16 1.0
#define SENT_C 1.0e6f

#define PTW 4     // point-tiles per wave
#define WPB 4     // waves per block (256 threads)
#define FBLK 256

typedef __attribute__((ext_vector_type(8))) short short8;   // 8 bf16 (4 VGPRs)
typedef __attribute__((ext_vector_type(4))) float f32x4;

union FragCast { uint4 u; short8 s; };

// ---- bf16 helpers (RTN split: f = hi + lo to ~2^-17 relative) ----
__device__ __forceinline__ unsigned short bfh(float f) {
    unsigned u = __float_as_uint(f);
    return (unsigned short)((u + 0x7FFFu + ((u >> 16) & 1u)) >> 16);
}
__device__ __forceinline__ float bftof(unsigned short h) {
    return __uint_as_float(((unsigned)h) << 16);
}
__device__ __forceinline__ unsigned short bfl(float f, unsigned short h) {
    return bfh(f - bftof(h));
}
__device__ __forceinline__ unsigned pk(unsigned short lo, unsigned short hi) {
    return (unsigned)lo | ((unsigned)hi << 16);
}

// K-slot packing (A row side holds point P={tx,ty,tz,p2}, t=-2p; B col side
// holds source V={vx,vy,vz,v2}). Sum over k of A[k]*B[k] =
//   k0-2 : t_hi.xyz * v_hi.xyz
//   k3-5 : t_lo.xyz * v_hi.xyz
//   k6-8 : t_hi.xyz * v_lo.xyz
//   k9-10: 1.0      * v2_hi, v2_lo
//   k11-12: p2_hi,p2_lo * 1.0
//   k13-31: zero (lanes 32-63 hold zero A-frags)
// => D[row][col] = |p|^2 + |v|^2 - 2 p.v  computed at ~fp32 precision.
__device__ __forceinline__ uint4 makeAfrag(float x, float y, float z, float w, int g) {
    unsigned short hx = bfh(x), hy = bfh(y), hz = bfh(z);
    uint4 r;
    if (g == 0) {
        unsigned short lx = bfl(x, hx), ly = bfl(y, hy), lz = bfl(z, hz);
        r.x = pk(hx, hy); r.y = pk(hz, lx); r.z = pk(ly, lz); r.w = pk(hx, hy);
    } else {
        unsigned short hw = bfh(w), lw = bfl(w, hw);
        r.x = pk(hz, ONEBF); r.y = pk(ONEBF, hw); r.z = pk(lw, 0); r.w = 0u;
    }
    return r;
}
__device__ __forceinline__ uint4 makeBfrag(float x, float y, float z, float w, int g) {
    unsigned short hx = bfh(x), hy = bfh(y), hz = bfh(z);
    uint4 r;
    if (g == 0) {
        unsigned short lx = bfl(x, hx), ly = bfl(y, hy);
        r.x = pk(hx, hy); r.y = pk(hz, hx); r.z = pk(hy, hz); r.w = pk(lx, ly);
    } else {
        unsigned short lz = bfl(z, hz);
        unsigned short hw = bfh(w), lw = bfl(w, hw);
        r.x = pk(lz, hw); r.y = pk(lw, ONEBF); r.z = pk(ONEBF, 0); r.w = 0u;
    }
    return r;
}

// ---------------- kernel 0: prep (build all MFMA fragments + init) ----------------
// One thread per (array, tile, lane<32); trailing range inits min arrays + acc.
__global__ void prep_kernel(const float* __restrict__ overts,
                            const int* __restrict__ ofaces,
                            const float* __restrict__ sverts,
                            const int* __restrict__ sfaces,
                            const float* __restrict__ u1,
                            const float* __restrict__ u2,
                            uint4* __restrict__ revA, uint4* __restrict__ fwdA,
                            uint4* __restrict__ revB, uint4* __restrict__ fwdB,
                            unsigned* __restrict__ rev_min,
                            unsigned* __restrict__ fwd_min,
                            float* __restrict__ acc,
                            int n_orig, int f_orig, int fs, int S, int npts,
                            int revPt, int fwdPt, int revSt, int fwdSt) {
    int tid = blockIdx.x * blockDim.x + threadIdx.x;
    const float third = 1.0f / 3.0f;
    int r0 = revPt * 32, r1 = r0 + fwdPt * 32, r2 = r1 + revSt * 32, r3 = r2 + fwdSt * 32;

    if (tid < r0) {
        // rev A-frags: sampled points
        int l = tid & 31, g = l >> 4;
        int k = (tid >> 5) * 16 + (l & 15);
        float x = 0.f, y = 0.f, z = 0.f;
        if (k < npts) {
            int f = k / S;
            float rr = sqrtf(u1[k]);
            float uu = u2[k];
            float wa = 1.0f - rr, wb = rr * (1.0f - uu), wc = rr * uu;
            int a = sfaces[3 * f], b = sfaces[3 * f + 1], c = sfaces[3 * f + 2];
            x = wa * sverts[3 * a] + wb * sverts[3 * b] + wc * sverts[3 * c];
            y = wa * sverts[3 * a + 1] + wb * sverts[3 * b + 1] + wc * sverts[3 * c + 1];
            z = wa * sverts[3 * a + 2] + wb * sverts[3 * b + 2] + wc * sverts[3 * c + 2];
        }
        float p2 = x * x + y * y + z * z;
        revA[tid] = makeAfrag(-2.f * x, -2.f * y, -2.f * z, p2, g);
    } else if (tid < r1) {
        // fwd A-frags: simplified barycenters
        int t2 = tid - r0;
        int l = t2 & 31, g = l >> 4;
        int k = (t2 >> 5) * 16 + (l & 15);
        float x = 0.f, y = 0.f, z = 0.f;
        if (k < fs) {
            int a = sfaces[3 * k], b = sfaces[3 * k + 1], c = sfaces[3 * k + 2];
            x = (sverts[3 * a] + sverts[3 * b] + sverts[3 * c]) * third;
            y = (sverts[3 * a + 1] + sverts[3 * b + 1] + sverts[3 * c + 1]) * third;
            z = (sverts[3 * a + 2] + sverts[3 * b + 2] + sverts[3 * c + 2]) * third;
        }
        float p2 = x * x + y * y + z * z;
        fwdA[t2] = makeAfrag(-2.f * x, -2.f * y, -2.f * z, p2, g);
    } else if (tid < r2) {
        // rev B-frags: original vertices
        int t2 = tid - r1;
        int l = t2 & 31, g = l >> 4;
        int s = (t2 >> 5) * 16 + (l & 15);
        float x = SENT_C, y = SENT_C, z = SENT_C;
        if (s < n_orig) { x = overts[3 * s]; y = overts[3 * s + 1]; z = overts[3 * s + 2]; }
        revB[t2] = makeBfrag(x, y, z, x * x + y * y + z * z, g);
    } else if (tid < r3) {
        // fwd B-frags: original barycenters
        int t2 = tid - r2;
        int l = t2 & 31, g = l >> 4;
        int s = (t2 >> 5) * 16 + (l & 15);
        float x = SENT_C, y = SENT_C, z = SENT_C;
        if (s < f_orig) {
            int a = ofaces[3 * s], b = ofaces[3 * s + 1], c = ofaces[3 * s + 2];
            x = (overts[3 * a] + overts[3 * b] + overts[3 * c]) * third;
            y = (overts[3 * a + 1] + overts[3 * b + 1] + overts[3 * c + 1]) * third;
            z = (overts[3 * a + 2] + overts[3 * b + 2] + overts[3 * c + 2]) * third;
        }
        fwdB[t2] = makeBfrag(x, y, z, x * x + y * y + z * z, g);
    } else {
        int t2 = tid - r3;
        if (t2 < npts) rev_min[t2] = INFBITS;
        if (t2 < fs)   fwd_min[t2] = INFBITS;
        if (t2 < 8)    acc[t2] = 0.0f;
    }
}

// ---------------- kernel 1: MFMA min-distance ----------------
// Wave gw: first revWaves waves do the reverse term, rest forward. Each wave
// owns PTW point-tiles (A-frags, loaded once) and streams `cs` source-tiles
// (B-frags, 512B each from L2), doing one mfma per (ptile, stile) with C=0.
// D[row][col] = d^2; running min per acc-reg; final col-reduce via shfl_xor;
// chunk results merged with atomicMin on float bits (clamped >= 0).
__global__ void __launch_bounds__(256)
mfma_min_kernel(const uint4* __restrict__ revA, const uint4* __restrict__ fwdA,
                const uint4* __restrict__ revB, const uint4* __restrict__ fwdB,
                unsigned* __restrict__ rev_min, unsigned* __restrict__ fwd_min,
                int revGroups, int revWaves, int revPt, int revNpts, int revSt, int revCS,
                int fwdGroups, int fwdPt, int fwdNpts, int fwdSt, int fwdCS,
                int totalWaves) {
    int gw = blockIdx.x * WPB + ((int)threadIdx.x >> 6);
    if (gw >= totalWaves) return;
    int lane = (int)threadIdx.x & 63;

    const uint4 *A, *B;
    unsigned* omin;
    int group, chunk, cs, nTile, npts, nst;
    if (gw < revWaves) {
        A = revA; B = revB; omin = rev_min; nTile = revPt; npts = revNpts; nst = revSt;
        cs = revCS; group = gw % revGroups; chunk = gw / revGroups;
    } else {
        int g2 = gw - revWaves;
        A = fwdA; B = fwdB; omin = fwd_min; nTile = fwdPt; npts = fwdNpts; nst = fwdSt;
        cs = fwdCS; group = g2 % fwdGroups; chunk = g2 / fwdGroups;
    }
    int s0 = chunk * cs;
    int ns = min(cs, nst - s0);

    // load A-frags (lanes 0-31; lanes 32-63 zero => k16-31 contribute nothing)
    short8 a[PTW]; int pt[PTW];
    #pragma unroll
    for (int r = 0; r < PTW; ++r) {
        int ptile = min(group * PTW + r, nTile - 1);
        pt[r] = ptile;
        FragCast fc; fc.u = make_uint4(0u, 0u, 0u, 0u);
        if (lane < 32) fc.u = A[ptile * 32 + lane];
        a[r] = fc.s;
    }

    float inf = __uint_as_float(INFBITS);
    f32x4 m0 = {inf, inf, inf, inf}, m1 = m0, m2 = m0, m3 = m0;
    f32x4 cz = {0.f, 0.f, 0.f, 0.f};
    const uint4* bp = B + (size_t)s0 * 32 + (lane & 31);

    for (int s = 0; s < ns; ++s) {
        FragCast fb; fb.u = bp[(size_t)s * 32];
        short8 b = fb.s;
        f32x4 d0 = __builtin_amdgcn_mfma_f32_16x16x32_bf16(a[0], b, cz, 0, 0, 0);
        f32x4 d1 = __builtin_amdgcn_mfma_f32_16x16x32_bf16(a[1], b, cz, 0, 0, 0);
        f32x4 d2 = __builtin_amdgcn_mfma_f32_16x16x32_bf16(a[2], b, cz, 0, 0, 0);
        f32x4 d3 = __builtin_amdgcn_mfma_f32_16x16x32_bf16(a[3], b, cz, 0, 0, 0);
        m0.x = fminf(m0.x, d0.x); m0.y = fminf(m0.y, d0.y); m0.z = fminf(m0.z, d0.z); m0.w = fminf(m0.w, d0.w);
        m1.x = fminf(m1.x, d1.x); m1.y = fminf(m1.y, d1.y); m1.z = fminf(m1.z, d1.z); m1.w = fminf(m1.w, d1.w);
        m2.x = fminf(m2.x, d2.x); m2.y = fminf(m2.y, d2.y); m2.z = fminf(m2.z, d2.z); m2.w = fminf(m2.w, d2.w);
        m3.x = fminf(m3.x, d3.x); m3.y = fminf(m3.y, d3.y); m3.z = fminf(m3.z, d3.z); m3.w = fminf(m3.w, d3.w);
    }

    // min over the 16 cols = min across the 16 lanes of each lane-group
    #pragma unroll
    for (int off = 1; off < 16; off <<= 1) {
        m0.x = fminf(m0.x, __shfl_xor(m0.x, off)); m0.y = fminf(m0.y, __shfl_xor(m0.y, off));
        m0.z = fminf(m0.z, __shfl_xor(m0.z, off)); m0.w = fminf(m0.w, __shfl_xor(m0.w, off));
        m1.x = fminf(m1.x, __shfl_xor(m1.x, off)); m1.y = fminf(m1.y, __shfl_xor(m1.y, off));
        m1.z = fminf(m1.z, __shfl_xor(m1.z, off)); m1.w = fminf(m1.w, __shfl_xor(m1.w, off));
        m2.x = fminf(m2.x, __shfl_xor(m2.x, off)); m2.y = fminf(m2.y, __shfl_xor(m2.y, off));
        m2.z = fminf(m2.z, __shfl_xor(m2.z, off)); m2.w = fminf(m2.w, __shfl_xor(m2.w, off));
        m3.x = fminf(m3.x, __shfl_xor(m3.x, off)); m3.y = fminf(m3.y, __shfl_xor(m3.y, off));
        m3.z = fminf(m3.z, __shfl_xor(m3.z, off)); m3.w = fminf(m3.w, __shfl_xor(m3.w, off));
    }

    if ((lane & 15) == 0) {
        int rowbase = (lane >> 4) * 4;   // D row = (lane>>4)*4 + reg
        #pragma unroll
        for (int r = 0; r < PTW; ++r) {
            f32x4 mm = (r == 0) ? m0 : (r == 1) ? m1 : (r == 2) ? m2 : m3;
            int pb = pt[r] * 16 + rowbase;
            if (pb + 0 < npts) atomicMin(&omin[pb + 0], __float_as_uint(fmaxf(mm.x, 0.f)));
            if (pb + 1 < npts) atomicMin(&omin[pb + 1], __float_as_uint(fmaxf(mm.y, 0.f)));
            if (pb + 2 < npts) atomicMin(&omin[pb + 2], __float_as_uint(fmaxf(mm.z, 0.f)));
            if (pb + 3 < npts) atomicMin(&omin[pb + 3], __float_as_uint(fmaxf(mm.w, 0.f)));
        }
    }
}

// ---------------- kernel 2: reductions + final scalar (last-block writes out) ----------------
__global__ void finalize_kernel(const unsigned int* __restrict__ fwd_min,
                                const unsigned int* __restrict__ rev_min,
                                const float* __restrict__ fp,
                                float* acc, float* out,
                                int fs, int npts, int S, int nblocks) {
    __shared__ float s1[FBLK], s2[FBLK], s3[FBLK];
    int k = blockIdx.x * blockDim.x + threadIdx.x;
    float fsum = 0.f, rsum = 0.f, rmax = 0.f;
    if (k < npts) {
        float md = __uint_as_float(rev_min[k]);
        float p = fp[k / S];
        rsum = p * md;
        rmax = md;
    }
    if (k < fs) {
        float p = fp[k];
        fsum = p * __uint_as_float(fwd_min[k]) + PROB_PENALTYF * (1.0f - p);
    }
    s1[threadIdx.x] = fsum;
    s2[threadIdx.x] = rsum;
    s3[threadIdx.x] = rmax;
    __syncthreads();
    for (int off = FBLK / 2; off > 0; off >>= 1) {
        if ((int)threadIdx.x < off) {
            s1[threadIdx.x] += s1[threadIdx.x + off];
            s2[threadIdx.x] += s2[threadIdx.x + off];
            s3[threadIdx.x] = fmaxf(s3[threadIdx.x], s3[threadIdx.x + off]);
        }
        __syncthreads();
    }
    if (threadIdx.x == 0) {
        atomicAdd(&acc[0], s1[0]);
        atomicAdd(&acc[1], s2[0]);
        atomicMax((unsigned int*)&acc[2], __float_as_uint(s3[0]));
        __threadfence();
        unsigned int ticket = atomicAdd((unsigned int*)&acc[3], 1u);
        if (ticket == (unsigned int)(nblocks - 1)) {
            __threadfence();
            float a0 = atomicAdd(&acc[0], 0.0f);
            float a1 = atomicAdd(&acc[1], 0.0f);
            unsigned int mb = atomicOr((unsigned int*)&acc[2], 0u);
            out[0] = a0 + a1 * (REV_SCALEF / (__uint_as_float(mb) + EPSF));
        }
    }
}

extern "C" void kernel_launch(void* const* d_in, const int* in_sizes, int n_in,
                              void* d_out, int out_size, void* d_ws, size_t ws_size,
                              hipStream_t stream) {
    const float* overts = (const float*)d_in[0];
    const int*   ofaces = (const int*)d_in[1];
    const float* sverts = (const float*)d_in[2];
    const int*   sfaces = (const int*)d_in[3];
    const float* fp     = (const float*)d_in[4];
    const float* u1     = (const float*)d_in[5];
    const float* u2     = (const float*)d_in[6];
    float* out = (float*)d_out;

    const int N_ORIG = in_sizes[0] / 3;
    const int F_ORIG = in_sizes[1] / 3;
    const int F_SIMP = in_sizes[3] / 3;
    const int S      = in_sizes[5] / F_SIMP;
    const int NPTS   = F_SIMP * S;

    // tile counts (16 points/sources per tile)
    const int revPt = (NPTS + 15) / 16;      // 2000
    const int fwdPt = (F_SIMP + 15) / 16;    // 250
    const int revSt = (N_ORIG + 15) / 16;    // 500
    const int fwdSt = (F_ORIG + 15) / 16;    // 1000

    // workspace: revA | fwdA | revB | fwdB | rev_min | fwd_min | acc
    uint4* revA = (uint4*)d_ws;
    uint4* fwdA = revA + (size_t)revPt * 32;
    uint4* revB = fwdA + (size_t)fwdPt * 32;
    uint4* fwdB = revB + (size_t)revSt * 32;
    unsigned* rev_min = (unsigned*)(fwdB + (size_t)fwdSt * 32);
    unsigned* fwd_min = rev_min + NPTS;
    float* acc = (float*)(fwd_min + F_SIMP);

    // ---- prep ----
    int prepThreads = (revPt + fwdPt + revSt + fwdSt) * 32 + NPTS;
    hipLaunchKernelGGL(prep_kernel, dim3((prepThreads + 255) / 256), dim3(256), 0, stream,
                       overts, ofaces, sverts, sfaces, u1, u2,
                       revA, fwdA, revB, fwdB, rev_min, fwd_min, acc,
                       N_ORIG, F_ORIG, F_SIMP, S, NPTS,
                       revPt, fwdPt, revSt, fwdSt);

    // ---- mfma min ----
    // rev: 500 groups x 4 chunks (125 stiles) = 2000 waves
    // fwd: 63 groups x 8 chunks (125 stiles) = 504 waves
    const int revGroups = (revPt + PTW - 1) / PTW;
    const int revChunks = (revSt >= 500) ? 4 : 1;
    const int revCS = (revSt + revChunks - 1) / revChunks;
    const int revWaves = revGroups * revChunks;

    const int fwdGroups = (fwdPt + PTW - 1) / PTW;
    const int fwdChunks = (fwdSt >= 1000) ? 8 : 1;
    const int fwdCS = (fwdSt + fwdChunks - 1) / fwdChunks;
    const int fwdWaves = fwdGroups * fwdChunks;

    const int totalWaves = revWaves + fwdWaves;
    const int mblocks = (totalWaves + WPB - 1) / WPB;
    hipLaunchKernelGGL(mfma_min_kernel, dim3(mblocks), dim3(256), 0, stream,
                       revA, fwdA, revB, fwdB, rev_min, fwd_min,
                       revGroups, revWaves, revPt, NPTS, revSt, revCS,
                       fwdGroups, fwdPt, F_SIMP, fwdSt, fwdCS,
                       totalWaves);

    // ---- finalize ----
    const int finBlocks = (NPTS + FBLK - 1) / FBLK;
    hipLaunchKernelGGL(finalize_kernel, dim3(finBlocks), dim3(FBLK), 0, stream,
                       fwd_min, rev_min, fp, acc, out, F_SIMP, NPTS, S, finBlocks);
}

// Round 9
// 52.563 us; speedup vs baseline: 1.5266x; 1.5266x over previous
//
#include <hip/hip_runtime.h>

#define EPSF 1e-8f
#define PROB_PENALTYF 1e-4f
#define REV_SCALEF 0.1f
#define INFBITS 0x7F800000u
#define ONEBF ((unsigned short)0x3F80)   // bf16 1.0
#define SENT_C 1.0e6f

#define PTW 8     // point-tiles per wave
#define WPB 4     // waves per block (256 threads)
#define FBLK 256

typedef __attribute__((ext_vector_type(8))) short short8;   // 8 bf16 (4 VGPRs)
typedef __attribute__((ext_vector_type(4))) float f32x4;

union FragCast { uint4 u; short8 s; };

// ---- bf16 helpers (RTN split: f = hi + lo to ~2^-17 relative) ----
__device__ __forceinline__ unsigned short bfh(float f) {
    unsigned u = __float_as_uint(f);
    return (unsigned short)((u + 0x7FFFu + ((u >> 16) & 1u)) >> 16);
}
__device__ __forceinline__ float bftof(unsigned short h) {
    return __uint_as_float(((unsigned)h) << 16);
}
__device__ __forceinline__ unsigned short bfl(float f, unsigned short h) {
    return bfh(f - bftof(h));
}
__device__ __forceinline__ unsigned pk(unsigned short lo, unsigned short hi) {
    return (unsigned)lo | ((unsigned)hi << 16);
}

// K-slot packing (A row side holds point P={tx,ty,tz,p2}, t=-2p; B col side
// holds source V={vx,vy,vz,v2}). Sum over k of A[k]*B[k] =
//   k0-2 : t_hi.xyz * v_hi.xyz
//   k3-5 : t_lo.xyz * v_hi.xyz
//   k6-8 : t_hi.xyz * v_lo.xyz
//   k9-10: 1.0      * v2_hi, v2_lo
//   k11-12: p2_hi,p2_lo * 1.0
//   k13-31: zero (lanes 32-63 hold zero A-frags)
// => D[row][col] = |p|^2 + |v|^2 - 2 p.v  computed at ~fp32 precision.
__device__ __forceinline__ uint4 makeAfrag(float x, float y, float z, float w, int g) {
    unsigned short hx = bfh(x), hy = bfh(y), hz = bfh(z);
    uint4 r;
    if (g == 0) {
        unsigned short lx = bfl(x, hx), ly = bfl(y, hy), lz = bfl(z, hz);
        r.x = pk(hx, hy); r.y = pk(hz, lx); r.z = pk(ly, lz); r.w = pk(hx, hy);
    } else {
        unsigned short hw = bfh(w), lw = bfl(w, hw);
        r.x = pk(hz, ONEBF); r.y = pk(ONEBF, hw); r.z = pk(lw, 0); r.w = 0u;
    }
    return r;
}
__device__ __forceinline__ uint4 makeBfrag(float x, float y, float z, float w, int g) {
    unsigned short hx = bfh(x), hy = bfh(y), hz = bfh(z);
    uint4 r;
    if (g == 0) {
        unsigned short lx = bfl(x, hx), ly = bfl(y, hy);
        r.x = pk(hx, hy); r.y = pk(hz, hx); r.z = pk(hy, hz); r.w = pk(lx, ly);
    } else {
        unsigned short lz = bfl(z, hz);
        unsigned short hw = bfh(w), lw = bfl(w, hw);
        r.x = pk(lz, hw); r.y = pk(lw, ONEBF); r.z = pk(ONEBF, 0); r.w = 0u;
    }
    return r;
}

// ---------------- kernel 0: prep (build all MFMA fragments + init) ----------------
__global__ void prep_kernel(const float* __restrict__ overts,
                            const int* __restrict__ ofaces,
                            const float* __restrict__ sverts,
                            const int* __restrict__ sfaces,
                            const float* __restrict__ u1,
                            const float* __restrict__ u2,
                            uint4* __restrict__ revA, uint4* __restrict__ fwdA,
                            uint4* __restrict__ revB, uint4* __restrict__ fwdB,
                            unsigned* __restrict__ rev_min,
                            unsigned* __restrict__ fwd_min,
                            float* __restrict__ acc,
                            int n_orig, int f_orig, int fs, int S, int npts,
                            int revPt, int fwdPt, int revSt, int fwdSt) {
    int tid = blockIdx.x * blockDim.x + threadIdx.x;
    const float third = 1.0f / 3.0f;
    int r0 = revPt * 32, r1 = r0 + fwdPt * 32, r2 = r1 + revSt * 32, r3 = r2 + fwdSt * 32;

    if (tid < r0) {
        int l = tid & 31, g = l >> 4;
        int k = (tid >> 5) * 16 + (l & 15);
        float x = 0.f, y = 0.f, z = 0.f;
        if (k < npts) {
            int f = k / S;
            float rr = sqrtf(u1[k]);
            float uu = u2[k];
            float wa = 1.0f - rr, wb = rr * (1.0f - uu), wc = rr * uu;
            int a = sfaces[3 * f], b = sfaces[3 * f + 1], c = sfaces[3 * f + 2];
            x = wa * sverts[3 * a] + wb * sverts[3 * b] + wc * sverts[3 * c];
            y = wa * sverts[3 * a + 1] + wb * sverts[3 * b + 1] + wc * sverts[3 * c + 1];
            z = wa * sverts[3 * a + 2] + wb * sverts[3 * b + 2] + wc * sverts[3 * c + 2];
        }
        float p2 = x * x + y * y + z * z;
        revA[tid] = makeAfrag(-2.f * x, -2.f * y, -2.f * z, p2, g);
    } else if (tid < r1) {
        int t2 = tid - r0;
        int l = t2 & 31, g = l >> 4;
        int k = (t2 >> 5) * 16 + (l & 15);
        float x = 0.f, y = 0.f, z = 0.f;
        if (k < fs) {
            int a = sfaces[3 * k], b = sfaces[3 * k + 1], c = sfaces[3 * k + 2];
            x = (sverts[3 * a] + sverts[3 * b] + sverts[3 * c]) * third;
            y = (sverts[3 * a + 1] + sverts[3 * b + 1] + sverts[3 * c + 1]) * third;
            z = (sverts[3 * a + 2] + sverts[3 * b + 2] + sverts[3 * c + 2]) * third;
        }
        float p2 = x * x + y * y + z * z;
        fwdA[t2] = makeAfrag(-2.f * x, -2.f * y, -2.f * z, p2, g);
    } else if (tid < r2) {
        int t2 = tid - r1;
        int l = t2 & 31, g = l >> 4;
        int s = (t2 >> 5) * 16 + (l & 15);
        float x = SENT_C, y = SENT_C, z = SENT_C;
        if (s < n_orig) { x = overts[3 * s]; y = overts[3 * s + 1]; z = overts[3 * s + 2]; }
        revB[t2] = makeBfrag(x, y, z, x * x + y * y + z * z, g);
    } else if (tid < r3) {
        int t2 = tid - r2;
        int l = t2 & 31, g = l >> 4;
        int s = (t2 >> 5) * 16 + (l & 15);
        float x = SENT_C, y = SENT_C, z = SENT_C;
        if (s < f_orig) {
            int a = ofaces[3 * s], b = ofaces[3 * s + 1], c = ofaces[3 * s + 2];
            x = (overts[3 * a] + overts[3 * b] + overts[3 * c]) * third;
            y = (overts[3 * a + 1] + overts[3 * b + 1] + overts[3 * c + 1]) * third;
            z = (overts[3 * a + 2] + overts[3 * b + 2] + overts[3 * c + 2]) * third;
        }
        fwdB[t2] = makeBfrag(x, y, z, x * x + y * y + z * z, g);
    } else {
        int t2 = tid - r3;
        if (t2 < npts) rev_min[t2] = INFBITS;
        if (t2 < fs)   fwd_min[t2] = INFBITS;
        if (t2 < 8)    acc[t2] = 0.0f;
    }
}

// ---------------- kernel 1: MFMA min-distance (prefetch depth 2, PTW=8) ----------------
__global__ void __launch_bounds__(256)
mfma_min_kernel(const uint4* __restrict__ revA, const uint4* __restrict__ fwdA,
                const uint4* __restrict__ revB, const uint4* __restrict__ fwdB,
                unsigned* __restrict__ rev_min, unsigned* __restrict__ fwd_min,
                int revGroups, int revWaves, int revPt, int revNpts, int revSt, int revCS,
                int fwdGroups, int fwdPt, int fwdNpts, int fwdSt, int fwdCS,
                int totalWaves) {
    int gw = blockIdx.x * WPB + ((int)threadIdx.x >> 6);
    if (gw >= totalWaves) return;
    int lane = (int)threadIdx.x & 63;

    const uint4 *A, *B;
    unsigned* omin;
    int group, chunk, cs, nTile, npts, nst;
    if (gw < revWaves) {
        A = revA; B = revB; omin = rev_min; nTile = revPt; npts = revNpts; nst = revSt;
        cs = revCS; group = gw % revGroups; chunk = gw / revGroups;
    } else {
        int g2 = gw - revWaves;
        A = fwdA; B = fwdB; omin = fwd_min; nTile = fwdPt; npts = fwdNpts; nst = fwdSt;
        cs = fwdCS; group = g2 % fwdGroups; chunk = g2 / fwdGroups;
    }
    int s0 = chunk * cs;
    int ns = min(cs, nst - s0);

    // load A-frags (lanes 0-31; lanes 32-63 zero => k16-31 contribute nothing)
    short8 a[PTW]; int pt[PTW];
    #pragma unroll
    for (int r = 0; r < PTW; ++r) {
        int ptile = min(group * PTW + r, nTile - 1);
        pt[r] = ptile;
        FragCast fc; fc.u = make_uint4(0u, 0u, 0u, 0u);
        if (lane < 32) fc.u = A[ptile * 32 + lane];
        a[r] = fc.s;
    }

    float inf = __uint_as_float(INFBITS);
    f32x4 m[PTW];
    #pragma unroll
    for (int r = 0; r < PTW; ++r) m[r] = (f32x4){inf, inf, inf, inf};
    f32x4 cz = {0.f, 0.f, 0.f, 0.f};
    const uint4* bp = B + (size_t)s0 * 32 + (lane & 31);

#define COMPUTE(BF)                                                              \
    do {                                                                         \
        short8 bb = (BF).s;                                                      \
        _Pragma("unroll")                                                        \
        for (int r = 0; r < PTW; ++r) {                                          \
            f32x4 d = __builtin_amdgcn_mfma_f32_16x16x32_bf16(a[r], bb, cz, 0, 0, 0); \
            m[r].x = fminf(m[r].x, d.x); m[r].y = fminf(m[r].y, d.y);            \
            m[r].z = fminf(m[r].z, d.z); m[r].w = fminf(m[r].w, d.w);            \
        }                                                                        \
    } while (0)

    // prefetch depth 2, unroll 2. Prefetch may read up to 3 tiles past the
    // chunk end: valid workspace memory (next chunk / min arrays), discarded.
    FragCast b0, b1;
    b0.u = bp[0];
    b1.u = bp[32];
    int s = 0;
    for (; s + 2 <= ns; s += 2) {
        FragCast n0, n1;
        n0.u = bp[(s + 2) * 32];
        n1.u = bp[(s + 3) * 32];
        COMPUTE(b0);
        COMPUTE(b1);
        b0 = n0; b1 = n1;
    }
    if (s < ns) COMPUTE(b0);
#undef COMPUTE

    // min over the 16 cols = min across the 16 lanes of each lane-group
    #pragma unroll
    for (int off = 1; off < 16; off <<= 1) {
        #pragma unroll
        for (int r = 0; r < PTW; ++r) {
            m[r].x = fminf(m[r].x, __shfl_xor(m[r].x, off));
            m[r].y = fminf(m[r].y, __shfl_xor(m[r].y, off));
            m[r].z = fminf(m[r].z, __shfl_xor(m[r].z, off));
            m[r].w = fminf(m[r].w, __shfl_xor(m[r].w, off));
        }
    }

    if ((lane & 15) == 0) {
        int rowbase = (lane >> 4) * 4;   // D row = (lane>>4)*4 + reg
        #pragma unroll
        for (int r = 0; r < PTW; ++r) {
            int pb = pt[r] * 16 + rowbase;
            if (pb + 0 < npts) atomicMin(&omin[pb + 0], __float_as_uint(fmaxf(m[r].x, 0.f)));
            if (pb + 1 < npts) atomicMin(&omin[pb + 1], __float_as_uint(fmaxf(m[r].y, 0.f)));
            if (pb + 2 < npts) atomicMin(&omin[pb + 2], __float_as_uint(fmaxf(m[r].z, 0.f)));
            if (pb + 3 < npts) atomicMin(&omin[pb + 3], __float_as_uint(fmaxf(m[r].w, 0.f)));
        }
    }
}

// ---------------- kernel 2: reductions + final scalar (last-block writes out) ----------------
__global__ void finalize_kernel(const unsigned int* __restrict__ fwd_min,
                                const unsigned int* __restrict__ rev_min,
                                const float* __restrict__ fp,
                                float* acc, float* out,
                                int fs, int npts, int S, int nblocks) {
    __shared__ float s1[FBLK], s2[FBLK], s3[FBLK];
    int k = blockIdx.x * blockDim.x + threadIdx.x;
    float fsum = 0.f, rsum = 0.f, rmax = 0.f;
    if (k < npts) {
        float md = __uint_as_float(rev_min[k]);
        float p = fp[k / S];
        rsum = p * md;
        rmax = md;
    }
    if (k < fs) {
        float p = fp[k];
        fsum = p * __uint_as_float(fwd_min[k]) + PROB_PENALTYF * (1.0f - p);
    }
    s1[threadIdx.x] = fsum;
    s2[threadIdx.x] = rsum;
    s3[threadIdx.x] = rmax;
    __syncthreads();
    for (int off = FBLK / 2; off > 0; off >>= 1) {
        if ((int)threadIdx.x < off) {
            s1[threadIdx.x] += s1[threadIdx.x + off];
            s2[threadIdx.x] += s2[threadIdx.x + off];
            s3[threadIdx.x] = fmaxf(s3[threadIdx.x], s3[threadIdx.x + off]);
        }
        __syncthreads();
    }
    if (threadIdx.x == 0) {
        atomicAdd(&acc[0], s1[0]);
        atomicAdd(&acc[1], s2[0]);
        atomicMax((unsigned int*)&acc[2], __float_as_uint(s3[0]));
        __threadfence();
        unsigned int ticket = atomicAdd((unsigned int*)&acc[3], 1u);
        if (ticket == (unsigned int)(nblocks - 1)) {
            __threadfence();
            float a0 = atomicAdd(&acc[0], 0.0f);
            float a1 = atomicAdd(&acc[1], 0.0f);
            unsigned int mb = atomicOr((unsigned int*)&acc[2], 0u);
            out[0] = a0 + a1 * (REV_SCALEF / (__uint_as_float(mb) + EPSF));
        }
    }
}

extern "C" void kernel_launch(void* const* d_in, const int* in_sizes, int n_in,
                              void* d_out, int out_size, void* d_ws, size_t ws_size,
                              hipStream_t stream) {
    const float* overts = (const float*)d_in[0];
    const int*   ofaces = (const int*)d_in[1];
    const float* sverts = (const float*)d_in[2];
    const int*   sfaces = (const int*)d_in[3];
    const float* fp     = (const float*)d_in[4];
    const float* u1     = (const float*)d_in[5];
    const float* u2     = (const float*)d_in[6];
    float* out = (float*)d_out;

    const int N_ORIG = in_sizes[0] / 3;
    const int F_ORIG = in_sizes[1] / 3;
    const int F_SIMP = in_sizes[3] / 3;
    const int S      = in_sizes[5] / F_SIMP;
    const int NPTS   = F_SIMP * S;

    // tile counts (16 points/sources per tile)
    const int revPt = (NPTS + 15) / 16;      // 2000
    const int fwdPt = (F_SIMP + 15) / 16;    // 250
    const int revSt = (N_ORIG + 15) / 16;    // 500
    const int fwdSt = (F_ORIG + 15) / 16;    // 1000

    // workspace: revA | fwdA | revB | fwdB | rev_min | fwd_min | acc
    uint4* revA = (uint4*)d_ws;
    uint4* fwdA = revA + (size_t)revPt * 32;
    uint4* revB = fwdA + (size_t)fwdPt * 32;
    uint4* fwdB = revB + (size_t)revSt * 32;
    unsigned* rev_min = (unsigned*)(fwdB + (size_t)fwdSt * 32);
    unsigned* fwd_min = rev_min + NPTS;
    float* acc = (float*)(fwd_min + F_SIMP);

    // ---- prep ----
    int prepThreads = (revPt + fwdPt + revSt + fwdSt) * 32 + NPTS;
    hipLaunchKernelGGL(prep_kernel, dim3((prepThreads + 255) / 256), dim3(256), 0, stream,
                       overts, ofaces, sverts, sfaces, u1, u2,
                       revA, fwdA, revB, fwdB, rev_min, fwd_min, acc,
                       N_ORIG, F_ORIG, F_SIMP, S, NPTS,
                       revPt, fwdPt, revSt, fwdSt);

    // ---- mfma min ----
    // rev: 250 groups x 8 chunks (63 stiles) = 2000 waves
    // fwd: 32 groups x 16 chunks (63 stiles) = 512 waves
    const int revGroups = (revPt + PTW - 1) / PTW;
    const int revChunks = 8;
    const int revCS = (revSt + revChunks - 1) / revChunks;
    const int revWaves = revGroups * revChunks;

    const int fwdGroups = (fwdPt + PTW - 1) / PTW;
    const int fwdChunks = 16;
    const int fwdCS = (fwdSt + fwdChunks - 1) / fwdChunks;
    const int fwdWaves = fwdGroups * fwdChunks;

    const int totalWaves = revWaves + fwdWaves;
    const int mblocks = (totalWaves + WPB - 1) / WPB;
    hipLaunchKernelGGL(mfma_min_kernel, dim3(mblocks), dim3(256), 0, stream,
                       revA, fwdA, revB, fwdB, rev_min, fwd_min,
                       revGroups, revWaves, revPt, NPTS, revSt, revCS,
                       fwdGroups, fwdPt, F_SIMP, fwdSt, fwdCS,
                       totalWaves);

    // ---- finalize ----
    const int finBlocks = (NPTS + FBLK - 1) / FBLK;
    hipLaunchKernelGGL(finalize_kernel, dim3(finBlocks), dim3(FBLK), 0, stream,
                       fwd_min, rev_min, fp, acc, out, F_SIMP, NPTS, S, finBlocks);
}

// Round 10
// 46.687 us; speedup vs baseline: 1.7187x; 1.1259x over previous
//
#include <hip/hip_runtime.h>

#define EPSF 1e-8f
#define PROB_PENALTYF 1e-4f
#define REV_SCALEF 0.1f
#define INFBITS 0x7F800000u
#define ONEBF ((unsigned short)0x3F80)   // bf16 1.0
#define SENT_C 1.0e6f

#define PTW 8     // point-tiles per wave
#define WPB 4     // waves per block (256 threads)
#define FBLK 256

typedef __attribute__((ext_vector_type(8))) short short8;   // 8 bf16 (4 VGPRs)
typedef __attribute__((ext_vector_type(4))) float f32x4;

// ---- bf16 helpers (RTN split: f = hi + lo to ~2^-17 relative) ----
__device__ __forceinline__ unsigned short bfh(float f) {
    unsigned u = __float_as_uint(f);
    return (unsigned short)((u + 0x7FFFu + ((u >> 16) & 1u)) >> 16);
}
__device__ __forceinline__ float bftof(unsigned short h) {
    return __uint_as_float(((unsigned)h) << 16);
}
__device__ __forceinline__ unsigned short bfl(float f, unsigned short h) {
    return bfh(f - bftof(h));
}
__device__ __forceinline__ unsigned pk(unsigned short lo, unsigned short hi) {
    return (unsigned)lo | ((unsigned)hi << 16);
}

// K-slot packing (A row side holds point P={tx,ty,tz,p2}, t=-2p; B col side
// holds source V={vx,vy,vz,v2}). Sum over k of A[k]*B[k] =
//   k0-2 : t_hi.xyz * v_hi.xyz
//   k3-5 : t_lo.xyz * v_hi.xyz
//   k6-8 : t_hi.xyz * v_lo.xyz
//   k9-10: 1.0      * v2_hi, v2_lo
//   k11-12: p2_hi,p2_lo * 1.0
//   k13-31: zero (lanes 32-63 hold zero A-frags)
// => D[row][col] = |p|^2 + |v|^2 - 2 p.v  computed at ~fp32 precision.
__device__ __forceinline__ uint4 makeAfrag(float x, float y, float z, float w, int g) {
    unsigned short hx = bfh(x), hy = bfh(y), hz = bfh(z);
    uint4 r;
    if (g == 0) {
        unsigned short lx = bfl(x, hx), ly = bfl(y, hy), lz = bfl(z, hz);
        r.x = pk(hx, hy); r.y = pk(hz, lx); r.z = pk(ly, lz); r.w = pk(hx, hy);
    } else {
        unsigned short hw = bfh(w), lw = bfl(w, hw);
        r.x = pk(hz, ONEBF); r.y = pk(ONEBF, hw); r.z = pk(lw, 0); r.w = 0u;
    }
    return r;
}
__device__ __forceinline__ uint4 makeBfrag(float x, float y, float z, float w, int g) {
    unsigned short hx = bfh(x), hy = bfh(y), hz = bfh(z);
    uint4 r;
    if (g == 0) {
        unsigned short lx = bfl(x, hx), ly = bfl(y, hy);
        r.x = pk(hx, hy); r.y = pk(hz, hx); r.z = pk(hy, hz); r.w = pk(lx, ly);
    } else {
        unsigned short lz = bfl(z, hz);
        unsigned short hw = bfh(w), lw = bfl(w, hw);
        r.x = pk(lz, hw); r.y = pk(lw, ONEBF); r.z = pk(ONEBF, 0); r.w = 0u;
    }
    return r;
}

// ---------------- kernel 0: prep (build all MFMA fragments + init) ----------------
__global__ void prep_kernel(const float* __restrict__ overts,
                            const int* __restrict__ ofaces,
                            const float* __restrict__ sverts,
                            const int* __restrict__ sfaces,
                            const float* __restrict__ u1,
                            const float* __restrict__ u2,
                            uint4* __restrict__ revA, uint4* __restrict__ fwdA,
                            uint4* __restrict__ revB, uint4* __restrict__ fwdB,
                            unsigned* __restrict__ rev_min,
                            unsigned* __restrict__ fwd_min,
                            float* __restrict__ acc,
                            int n_orig, int f_orig, int fs, int S, int npts,
                            int revPt, int fwdPt, int revSt, int fwdSt) {
    int tid = blockIdx.x * blockDim.x + threadIdx.x;
    const float third = 1.0f / 3.0f;
    int r0 = revPt * 32, r1 = r0 + fwdPt * 32, r2 = r1 + revSt * 32, r3 = r2 + fwdSt * 32;

    if (tid < r0) {
        int l = tid & 31, g = l >> 4;
        int k = (tid >> 5) * 16 + (l & 15);
        float x = 0.f, y = 0.f, z = 0.f;
        if (k < npts) {
            int f = k / S;
            float rr = sqrtf(u1[k]);
            float uu = u2[k];
            float wa = 1.0f - rr, wb = rr * (1.0f - uu), wc = rr * uu;
            int a = sfaces[3 * f], b = sfaces[3 * f + 1], c = sfaces[3 * f + 2];
            x = wa * sverts[3 * a] + wb * sverts[3 * b] + wc * sverts[3 * c];
            y = wa * sverts[3 * a + 1] + wb * sverts[3 * b + 1] + wc * sverts[3 * c + 1];
            z = wa * sverts[3 * a + 2] + wb * sverts[3 * b + 2] + wc * sverts[3 * c + 2];
        }
        float p2 = x * x + y * y + z * z;
        revA[tid] = makeAfrag(-2.f * x, -2.f * y, -2.f * z, p2, g);
    } else if (tid < r1) {
        int t2 = tid - r0;
        int l = t2 & 31, g = l >> 4;
        int k = (t2 >> 5) * 16 + (l & 15);
        float x = 0.f, y = 0.f, z = 0.f;
        if (k < fs) {
            int a = sfaces[3 * k], b = sfaces[3 * k + 1], c = sfaces[3 * k + 2];
            x = (sverts[3 * a] + sverts[3 * b] + sverts[3 * c]) * third;
            y = (sverts[3 * a + 1] + sverts[3 * b + 1] + sverts[3 * c + 1]) * third;
            z = (sverts[3 * a + 2] + sverts[3 * b + 2] + sverts[3 * c + 2]) * third;
        }
        float p2 = x * x + y * y + z * z;
        fwdA[t2] = makeAfrag(-2.f * x, -2.f * y, -2.f * z, p2, g);
    } else if (tid < r2) {
        int t2 = tid - r1;
        int l = t2 & 31, g = l >> 4;
        int s = (t2 >> 5) * 16 + (l & 15);
        float x = SENT_C, y = SENT_C, z = SENT_C;
        if (s < n_orig) { x = overts[3 * s]; y = overts[3 * s + 1]; z = overts[3 * s + 2]; }
        revB[t2] = makeBfrag(x, y, z, x * x + y * y + z * z, g);
    } else if (tid < r3) {
        int t2 = tid - r2;
        int l = t2 & 31, g = l >> 4;
        int s = (t2 >> 5) * 16 + (l & 15);
        float x = SENT_C, y = SENT_C, z = SENT_C;
        if (s < f_orig) {
            int a = ofaces[3 * s], b = ofaces[3 * s + 1], c = ofaces[3 * s + 2];
            x = (overts[3 * a] + overts[3 * b] + overts[3 * c]) * third;
            y = (overts[3 * a + 1] + overts[3 * b + 1] + overts[3 * c + 1]) * third;
            z = (overts[3 * a + 2] + overts[3 * b + 2] + overts[3 * c + 2]) * third;
        }
        fwdB[t2] = makeBfrag(x, y, z, x * x + y * y + z * z, g);
    } else {
        int t2 = tid - r3;
        if (t2 < npts) rev_min[t2] = INFBITS;
        if (t2 < fs)   fwd_min[t2] = INFBITS;
        if (t2 < 8)    acc[t2] = 0.0f;
    }
}

// ---------------- kernel 1: MFMA min-distance (no unions, reg-only frags) ----------------
__global__ void __launch_bounds__(256, 2)
mfma_min_kernel(const uint4* __restrict__ revA, const uint4* __restrict__ fwdA,
                const uint4* __restrict__ revB, const uint4* __restrict__ fwdB,
                unsigned* __restrict__ rev_min, unsigned* __restrict__ fwd_min,
                int revGroups, int revWaves, int revPt, int revNpts, int revSt, int revCS,
                int fwdGroups, int fwdPt, int fwdNpts, int fwdSt, int fwdCS,
                int totalWaves) {
    int gw = blockIdx.x * WPB + ((int)threadIdx.x >> 6);
    if (gw >= totalWaves) return;
    int lane = (int)threadIdx.x & 63;

    const uint4 *A, *B;
    unsigned* omin;
    int group, chunk, cs, nTile, npts, nst;
    if (gw < revWaves) {
        A = revA; B = revB; omin = rev_min; nTile = revPt; npts = revNpts; nst = revSt;
        cs = revCS; group = gw % revGroups; chunk = gw / revGroups;
    } else {
        int g2 = gw - revWaves;
        A = fwdA; B = fwdB; omin = fwd_min; nTile = fwdPt; npts = fwdNpts; nst = fwdSt;
        cs = fwdCS; group = g2 % fwdGroups; chunk = g2 / fwdGroups;
    }
    int s0 = chunk * cs;
    int ns = min(cs, nst - s0);

    const short8* A8 = reinterpret_cast<const short8*>(A);
    const short8* B8 = reinterpret_cast<const short8*>(B);

    // load A-frags (lanes 0-31 hold data; lanes 32-63 zero => k16-31 dead)
    const short8 zero8 = {0, 0, 0, 0, 0, 0, 0, 0};
    short8 a[PTW];
    int pt0 = group * PTW;
    #pragma unroll
    for (int r = 0; r < PTW; ++r) {
        int ptile = min(pt0 + r, nTile - 1);
        short8 av = A8[ptile * 32 + (lane & 31)];
        a[r] = (lane < 32) ? av : zero8;
    }

    float inf = __uint_as_float(INFBITS);
    f32x4 m[PTW];
    #pragma unroll
    for (int r = 0; r < PTW; ++r) m[r] = (f32x4){inf, inf, inf, inf};
    f32x4 cz = {0.f, 0.f, 0.f, 0.f};
    const short8* bp = B8 + (size_t)s0 * 32 + (lane & 31);

#define COMPUTE(BB)                                                              \
    do {                                                                         \
        _Pragma("unroll")                                                        \
        for (int r = 0; r < PTW; ++r) {                                          \
            f32x4 d = __builtin_amdgcn_mfma_f32_16x16x32_bf16(a[r], (BB), cz, 0, 0, 0); \
            m[r].x = fminf(m[r].x, d.x); m[r].y = fminf(m[r].y, d.y);            \
            m[r].z = fminf(m[r].z, d.z); m[r].w = fminf(m[r].w, d.w);            \
        }                                                                        \
    } while (0)

    // prefetch depth 2, unroll 2. Prefetch may read up to 2 tiles past the
    // chunk end: valid workspace memory (next chunk / min arrays), discarded.
    short8 b0 = bp[0];
    short8 b1 = bp[32];
    int s = 0;
    for (; s + 2 <= ns; s += 2) {
        short8 n0 = bp[(s + 2) * 32];
        short8 n1 = bp[(s + 3) * 32];
        COMPUTE(b0);
        COMPUTE(b1);
        b0 = n0; b1 = n1;
    }
    if (s < ns) COMPUTE(b0);
#undef COMPUTE

    // min over the 16 cols = min across the 16 lanes of each lane-group
    #pragma unroll
    for (int off = 1; off < 16; off <<= 1) {
        #pragma unroll
        for (int r = 0; r < PTW; ++r) {
            m[r].x = fminf(m[r].x, __shfl_xor(m[r].x, off));
            m[r].y = fminf(m[r].y, __shfl_xor(m[r].y, off));
            m[r].z = fminf(m[r].z, __shfl_xor(m[r].z, off));
            m[r].w = fminf(m[r].w, __shfl_xor(m[r].w, off));
        }
    }

    if ((lane & 15) == 0) {
        int rowbase = (lane >> 4) * 4;   // D row = (lane>>4)*4 + reg
        #pragma unroll
        for (int r = 0; r < PTW; ++r) {
            int pb = min(pt0 + r, nTile - 1) * 16 + rowbase;
            if (pb + 0 < npts) atomicMin(&omin[pb + 0], __float_as_uint(fmaxf(m[r].x, 0.f)));
            if (pb + 1 < npts) atomicMin(&omin[pb + 1], __float_as_uint(fmaxf(m[r].y, 0.f)));
            if (pb + 2 < npts) atomicMin(&omin[pb + 2], __float_as_uint(fmaxf(m[r].z, 0.f)));
            if (pb + 3 < npts) atomicMin(&omin[pb + 3], __float_as_uint(fmaxf(m[r].w, 0.f)));
        }
    }
}

// ---------------- kernel 2: reductions + final scalar (last-block writes out) ----------------
__global__ void finalize_kernel(const unsigned int* __restrict__ fwd_min,
                                const unsigned int* __restrict__ rev_min,
                                const float* __restrict__ fp,
                                float* acc, float* out,
                                int fs, int npts, int S, int nblocks) {
    __shared__ float s1[FBLK], s2[FBLK], s3[FBLK];
    int k = blockIdx.x * blockDim.x + threadIdx.x;
    float fsum = 0.f, rsum = 0.f, rmax = 0.f;
    if (k < npts) {
        float md = __uint_as_float(rev_min[k]);
        float p = fp[k / S];
        rsum = p * md;
        rmax = md;
    }
    if (k < fs) {
        float p = fp[k];
        fsum = p * __uint_as_float(fwd_min[k]) + PROB_PENALTYF * (1.0f - p);
    }
    s1[threadIdx.x] = fsum;
    s2[threadIdx.x] = rsum;
    s3[threadIdx.x] = rmax;
    __syncthreads();
    for (int off = FBLK / 2; off > 0; off >>= 1) {
        if ((int)threadIdx.x < off) {
            s1[threadIdx.x] += s1[threadIdx.x + off];
            s2[threadIdx.x] += s2[threadIdx.x + off];
            s3[threadIdx.x] = fmaxf(s3[threadIdx.x], s3[threadIdx.x + off]);
        }
        __syncthreads();
    }
    if (threadIdx.x == 0) {
        atomicAdd(&acc[0], s1[0]);
        atomicAdd(&acc[1], s2[0]);
        atomicMax((unsigned int*)&acc[2], __float_as_uint(s3[0]));
        __threadfence();
        unsigned int ticket = atomicAdd((unsigned int*)&acc[3], 1u);
        if (ticket == (unsigned int)(nblocks - 1)) {
            __threadfence();
            float a0 = atomicAdd(&acc[0], 0.0f);
            float a1 = atomicAdd(&acc[1], 0.0f);
            unsigned int mb = atomicOr((unsigned int*)&acc[2], 0u);
            out[0] = a0 + a1 * (REV_SCALEF / (__uint_as_float(mb) + EPSF));
        }
    }
}

extern "C" void kernel_launch(void* const* d_in, const int* in_sizes, int n_in,
                              void* d_out, int out_size, void* d_ws, size_t ws_size,
                              hipStream_t stream) {
    const float* overts = (const float*)d_in[0];
    const int*   ofaces = (const int*)d_in[1];
    const float* sverts = (const float*)d_in[2];
    const int*   sfaces = (const int*)d_in[3];
    const float* fp     = (const float*)d_in[4];
    const float* u1     = (const float*)d_in[5];
    const float* u2     = (const float*)d_in[6];
    float* out = (float*)d_out;

    const int N_ORIG = in_sizes[0] / 3;
    const int F_ORIG = in_sizes[1] / 3;
    const int F_SIMP = in_sizes[3] / 3;
    const int S      = in_sizes[5] / F_SIMP;
    const int NPTS   = F_SIMP * S;

    // tile counts (16 points/sources per tile)
    const int revPt = (NPTS + 15) / 16;      // 2000
    const int fwdPt = (F_SIMP + 15) / 16;    // 250
    const int revSt = (N_ORIG + 15) / 16;    // 500
    const int fwdSt = (F_ORIG + 15) / 16;    // 1000

    // workspace: revA | fwdA | revB | fwdB | rev_min | fwd_min | acc
    uint4* revA = (uint4*)d_ws;
    uint4* fwdA = revA + (size_t)revPt * 32;
    uint4* revB = fwdA + (size_t)fwdPt * 32;
    uint4* fwdB = revB + (size_t)revSt * 32;
    unsigned* rev_min = (unsigned*)(fwdB + (size_t)fwdSt * 32);
    unsigned* fwd_min = rev_min + NPTS;
    float* acc = (float*)(fwd_min + F_SIMP);

    // ---- prep ----
    int prepThreads = (revPt + fwdPt + revSt + fwdSt) * 32 + NPTS;
    hipLaunchKernelGGL(prep_kernel, dim3((prepThreads + 255) / 256), dim3(256), 0, stream,
                       overts, ofaces, sverts, sfaces, u1, u2,
                       revA, fwdA, revB, fwdB, rev_min, fwd_min, acc,
                       N_ORIG, F_ORIG, F_SIMP, S, NPTS,
                       revPt, fwdPt, revSt, fwdSt);

    // ---- mfma min ----
    // rev: 250 groups x 8 chunks (63 stiles) = 2000 waves
    // fwd: 32 groups x 16 chunks (63 stiles) = 512 waves
    const int revGroups = (revPt + PTW - 1) / PTW;
    const int revChunks = 8;
    const int revCS = (revSt + revChunks - 1) / revChunks;
    const int revWaves = revGroups * revChunks;

    const int fwdGroups = (fwdPt + PTW - 1) / PTW;
    const int fwdChunks = 16;
    const int fwdCS = (fwdSt + fwdChunks - 1) / fwdChunks;
    const int fwdWaves = fwdGroups * fwdChunks;

    const int totalWaves = revWaves + fwdWaves;
    const int mblocks = (totalWaves + WPB - 1) / WPB;
    hipLaunchKernelGGL(mfma_min_kernel, dim3(mblocks), dim3(256), 0, stream,
                       revA, fwdA, revB, fwdB, rev_min, fwd_min,
                       revGroups, revWaves, revPt, NPTS, revSt, revCS,
                       fwdGroups, fwdPt, F_SIMP, fwdSt, fwdCS,
                       totalWaves);

    // ---- finalize ----
    const int finBlocks = (NPTS + FBLK - 1) / FBLK;
    hipLaunchKernelGGL(finalize_kernel, dim3(finBlocks), dim3(FBLK), 0, stream,
                       fwd_min, rev_min, fp, acc, out, F_SIMP, NPTS, S, finBlocks);
}

// Round 11
// 38.147 us; speedup vs baseline: 2.1035x; 1.2239x over previous
//
#include <hip/hip_runtime.h>

#define EPSF 1e-8f
#define PROB_PENALTYF 1e-4f
#define REV_SCALEF 0.1f
#define INFBITS 0x7F800000u
#define ONEBF ((unsigned short)0x3F80)   // bf16 1.0
#define SENT_C 1.0e6f

#define PTW 4     // point-tiles per wave (fits registers: a[4]+m[4]+8 bufs ~76 VGPR)
#define WPB 4     // waves per block (256 threads)
#define FBLK 256

typedef __attribute__((ext_vector_type(8))) short short8;   // 8 bf16 (4 VGPRs)
typedef __attribute__((ext_vector_type(4))) float f32x4;

// ---- bf16 helpers (RTN split: f = hi + lo to ~2^-17 relative) ----
__device__ __forceinline__ unsigned short bfh(float f) {
    unsigned u = __float_as_uint(f);
    return (unsigned short)((u + 0x7FFFu + ((u >> 16) & 1u)) >> 16);
}
__device__ __forceinline__ float bftof(unsigned short h) {
    return __uint_as_float(((unsigned)h) << 16);
}
__device__ __forceinline__ unsigned short bfl(float f, unsigned short h) {
    return bfh(f - bftof(h));
}
__device__ __forceinline__ unsigned pk(unsigned short lo, unsigned short hi) {
    return (unsigned)lo | ((unsigned)hi << 16);
}

// K-slot packing (A row side holds point P={tx,ty,tz,p2}, t=-2p; B col side
// holds source V={vx,vy,vz,v2}). Sum over k of A[k]*B[k] =
//   k0-2 : t_hi.xyz * v_hi.xyz
//   k3-5 : t_lo.xyz * v_hi.xyz
//   k6-8 : t_hi.xyz * v_lo.xyz
//   k9-10: 1.0      * v2_hi, v2_lo
//   k11-12: p2_hi,p2_lo * 1.0
//   k13-31: zero (lanes 32-63 hold zero A-frags)
// => D[row][col] = |p|^2 + |v|^2 - 2 p.v  computed at ~fp32 precision.
__device__ __forceinline__ uint4 makeAfrag(float x, float y, float z, float w, int g) {
    unsigned short hx = bfh(x), hy = bfh(y), hz = bfh(z);
    uint4 r;
    if (g == 0) {
        unsigned short lx = bfl(x, hx), ly = bfl(y, hy), lz = bfl(z, hz);
        r.x = pk(hx, hy); r.y = pk(hz, lx); r.z = pk(ly, lz); r.w = pk(hx, hy);
    } else {
        unsigned short hw = bfh(w), lw = bfl(w, hw);
        r.x = pk(hz, ONEBF); r.y = pk(ONEBF, hw); r.z = pk(lw, 0); r.w = 0u;
    }
    return r;
}
__device__ __forceinline__ uint4 makeBfrag(float x, float y, float z, float w, int g) {
    unsigned short hx = bfh(x), hy = bfh(y), hz = bfh(z);
    uint4 r;
    if (g == 0) {
        unsigned short lx = bfl(x, hx), ly = bfl(y, hy);
        r.x = pk(hx, hy); r.y = pk(hz, hx); r.z = pk(hy, hz); r.w = pk(lx, ly);
    } else {
        unsigned short lz = bfl(z, hz);
        unsigned short hw = bfh(w), lw = bfl(w, hw);
        r.x = pk(lz, hw); r.y = pk(lw, ONEBF); r.z = pk(ONEBF, 0); r.w = 0u;
    }
    return r;
}

// ---------------- kernel 0: prep (build all MFMA fragments + init) ----------------
__global__ void prep_kernel(const float* __restrict__ overts,
                            const int* __restrict__ ofaces,
                            const float* __restrict__ sverts,
                            const int* __restrict__ sfaces,
                            const float* __restrict__ u1,
                            const float* __restrict__ u2,
                            uint4* __restrict__ revA, uint4* __restrict__ fwdA,
                            uint4* __restrict__ revB, uint4* __restrict__ fwdB,
                            unsigned* __restrict__ rev_min,
                            unsigned* __restrict__ fwd_min,
                            float* __restrict__ acc,
                            int n_orig, int f_orig, int fs, int S, int npts,
                            int revPt, int fwdPt, int revSt, int fwdSt) {
    int tid = blockIdx.x * blockDim.x + threadIdx.x;
    const float third = 1.0f / 3.0f;
    int r0 = revPt * 32, r1 = r0 + fwdPt * 32, r2 = r1 + revSt * 32, r3 = r2 + fwdSt * 32;

    if (tid < r0) {
        int l = tid & 31, g = l >> 4;
        int k = (tid >> 5) * 16 + (l & 15);
        float x = 0.f, y = 0.f, z = 0.f;
        if (k < npts) {
            int f = k / S;
            float rr = sqrtf(u1[k]);
            float uu = u2[k];
            float wa = 1.0f - rr, wb = rr * (1.0f - uu), wc = rr * uu;
            int a = sfaces[3 * f], b = sfaces[3 * f + 1], c = sfaces[3 * f + 2];
            x = wa * sverts[3 * a] + wb * sverts[3 * b] + wc * sverts[3 * c];
            y = wa * sverts[3 * a + 1] + wb * sverts[3 * b + 1] + wc * sverts[3 * c + 1];
            z = wa * sverts[3 * a + 2] + wb * sverts[3 * b + 2] + wc * sverts[3 * c + 2];
        }
        float p2 = x * x + y * y + z * z;
        revA[tid] = makeAfrag(-2.f * x, -2.f * y, -2.f * z, p2, g);
    } else if (tid < r1) {
        int t2 = tid - r0;
        int l = t2 & 31, g = l >> 4;
        int k = (t2 >> 5) * 16 + (l & 15);
        float x = 0.f, y = 0.f, z = 0.f;
        if (k < fs) {
            int a = sfaces[3 * k], b = sfaces[3 * k + 1], c = sfaces[3 * k + 2];
            x = (sverts[3 * a] + sverts[3 * b] + sverts[3 * c]) * third;
            y = (sverts[3 * a + 1] + sverts[3 * b + 1] + sverts[3 * c + 1]) * third;
            z = (sverts[3 * a + 2] + sverts[3 * b + 2] + sverts[3 * c + 2]) * third;
        }
        float p2 = x * x + y * y + z * z;
        fwdA[t2] = makeAfrag(-2.f * x, -2.f * y, -2.f * z, p2, g);
    } else if (tid < r2) {
        int t2 = tid - r1;
        int l = t2 & 31, g = l >> 4;
        int s = (t2 >> 5) * 16 + (l & 15);
        float x = SENT_C, y = SENT_C, z = SENT_C;
        if (s < n_orig) { x = overts[3 * s]; y = overts[3 * s + 1]; z = overts[3 * s + 2]; }
        revB[t2] = makeBfrag(x, y, z, x * x + y * y + z * z, g);
    } else if (tid < r3) {
        int t2 = tid - r2;
        int l = t2 & 31, g = l >> 4;
        int s = (t2 >> 5) * 16 + (l & 15);
        float x = SENT_C, y = SENT_C, z = SENT_C;
        if (s < f_orig) {
            int a = ofaces[3 * s], b = ofaces[3 * s + 1], c = ofaces[3 * s + 2];
            x = (overts[3 * a] + overts[3 * b] + overts[3 * c]) * third;
            y = (overts[3 * a + 1] + overts[3 * b + 1] + overts[3 * c + 1]) * third;
            z = (overts[3 * a + 2] + overts[3 * b + 2] + overts[3 * c + 2]) * third;
        }
        fwdB[t2] = makeBfrag(x, y, z, x * x + y * y + z * z, g);
    } else {
        int t2 = tid - r3;
        if (t2 < npts) rev_min[t2] = INFBITS;
        if (t2 < fs)   fwd_min[t2] = INFBITS;
        if (t2 < 8)    acc[t2] = 0.0f;
    }
}

// ---------------- kernel 1: MFMA min-distance (PTW=4, depth-4 prefetch) ----------------
__global__ void __launch_bounds__(256, 4)
mfma_min_kernel(const uint4* __restrict__ revA, const uint4* __restrict__ fwdA,
                const uint4* __restrict__ revB, const uint4* __restrict__ fwdB,
                unsigned* __restrict__ rev_min, unsigned* __restrict__ fwd_min,
                int revGroups, int revWaves, int revPt, int revNpts, int revSt, int revCS,
                int fwdGroups, int fwdPt, int fwdNpts, int fwdSt, int fwdCS,
                int totalWaves) {
    int gw = blockIdx.x * WPB + ((int)threadIdx.x >> 6);
    if (gw >= totalWaves) return;
    int lane = (int)threadIdx.x & 63;

    const uint4 *A, *B;
    unsigned* omin;
    int group, chunk, cs, nTile, npts, nst;
    if (gw < revWaves) {
        A = revA; B = revB; omin = rev_min; nTile = revPt; npts = revNpts; nst = revSt;
        cs = revCS; group = gw % revGroups; chunk = gw / revGroups;
    } else {
        int g2 = gw - revWaves;
        A = fwdA; B = fwdB; omin = fwd_min; nTile = fwdPt; npts = fwdNpts; nst = fwdSt;
        cs = fwdCS; group = g2 % fwdGroups; chunk = g2 / fwdGroups;
    }
    int s0 = chunk * cs;
    int ns = min(cs, nst - s0);

    const short8* A8 = reinterpret_cast<const short8*>(A);
    const short8* B8 = reinterpret_cast<const short8*>(B);

    // load A-frags (lanes 0-31 hold data; lanes 32-63 zero => k16-31 dead)
    const short8 zero8 = {0, 0, 0, 0, 0, 0, 0, 0};
    short8 a[PTW];
    int pt0 = group * PTW;
    #pragma unroll
    for (int r = 0; r < PTW; ++r) {
        int ptile = min(pt0 + r, nTile - 1);
        short8 av = A8[ptile * 32 + (lane & 31)];
        a[r] = (lane < 32) ? av : zero8;
    }

    float inf = __uint_as_float(INFBITS);
    f32x4 m[PTW];
    #pragma unroll
    for (int r = 0; r < PTW; ++r) m[r] = (f32x4){inf, inf, inf, inf};
    f32x4 cz = {0.f, 0.f, 0.f, 0.f};
    const short8* bp = B8 + (size_t)s0 * 32 + (lane & 31);

#define COMPUTE(BB)                                                              \
    do {                                                                         \
        _Pragma("unroll")                                                        \
        for (int r = 0; r < PTW; ++r) {                                          \
            f32x4 d = __builtin_amdgcn_mfma_f32_16x16x32_bf16(a[r], (BB), cz, 0, 0, 0); \
            m[r].x = fminf(m[r].x, d.x); m[r].y = fminf(m[r].y, d.y);            \
            m[r].z = fminf(m[r].z, d.z); m[r].w = fminf(m[r].w, d.w);            \
        }                                                                        \
    } while (0)

    // prefetch depth 4, unroll 4. Prefetch may read up to 4 tiles past the
    // chunk end: valid workspace memory (next chunk / min arrays), discarded.
    short8 b0 = bp[0];
    short8 b1 = bp[32];
    short8 b2 = bp[64];
    short8 b3 = bp[96];
    int s = 0;
    for (; s + 4 <= ns; s += 4) {
        short8 n0 = bp[(s + 4) * 32];
        short8 n1 = bp[(s + 5) * 32];
        short8 n2 = bp[(s + 6) * 32];
        short8 n3 = bp[(s + 7) * 32];
        COMPUTE(b0);
        COMPUTE(b1);
        COMPUTE(b2);
        COMPUTE(b3);
        b0 = n0; b1 = n1; b2 = n2; b3 = n3;
    }
    if (s + 2 <= ns) {
        COMPUTE(b0);
        COMPUTE(b1);
        b0 = b2; b1 = b3;
        s += 2;
    }
    if (s < ns) COMPUTE(b0);
#undef COMPUTE

    // min over the 16 cols = min across the 16 lanes of each lane-group
    #pragma unroll
    for (int off = 1; off < 16; off <<= 1) {
        #pragma unroll
        for (int r = 0; r < PTW; ++r) {
            m[r].x = fminf(m[r].x, __shfl_xor(m[r].x, off));
            m[r].y = fminf(m[r].y, __shfl_xor(m[r].y, off));
            m[r].z = fminf(m[r].z, __shfl_xor(m[r].z, off));
            m[r].w = fminf(m[r].w, __shfl_xor(m[r].w, off));
        }
    }

    if ((lane & 15) == 0) {
        int rowbase = (lane >> 4) * 4;   // D row = (lane>>4)*4 + reg
        #pragma unroll
        for (int r = 0; r < PTW; ++r) {
            int pb = min(pt0 + r, nTile - 1) * 16 + rowbase;
            if (pb + 0 < npts) atomicMin(&omin[pb + 0], __float_as_uint(fmaxf(m[r].x, 0.f)));
            if (pb + 1 < npts) atomicMin(&omin[pb + 1], __float_as_uint(fmaxf(m[r].y, 0.f)));
            if (pb + 2 < npts) atomicMin(&omin[pb + 2], __float_as_uint(fmaxf(m[r].z, 0.f)));
            if (pb + 3 < npts) atomicMin(&omin[pb + 3], __float_as_uint(fmaxf(m[r].w, 0.f)));
        }
    }
}

// ---------------- kernel 2: reductions + final scalar (last-block writes out) ----------------
__global__ void finalize_kernel(const unsigned int* __restrict__ fwd_min,
                                const unsigned int* __restrict__ rev_min,
                                const float* __restrict__ fp,
                                float* acc, float* out,
                                int fs, int npts, int S, int nblocks) {
    __shared__ float s1[FBLK], s2[FBLK], s3[FBLK];
    int k = blockIdx.x * blockDim.x + threadIdx.x;
    float fsum = 0.f, rsum = 0.f, rmax = 0.f;
    if (k < npts) {
        float md = __uint_as_float(rev_min[k]);
        float p = fp[k / S];
        rsum = p * md;
        rmax = md;
    }
    if (k < fs) {
        float p = fp[k];
        fsum = p * __uint_as_float(fwd_min[k]) + PROB_PENALTYF * (1.0f - p);
    }
    s1[threadIdx.x] = fsum;
    s2[threadIdx.x] = rsum;
    s3[threadIdx.x] = rmax;
    __syncthreads();
    for (int off = FBLK / 2; off > 0; off >>= 1) {
        if ((int)threadIdx.x < off) {
            s1[threadIdx.x] += s1[threadIdx.x + off];
            s2[threadIdx.x] += s2[threadIdx.x + off];
            s3[threadIdx.x] = fmaxf(s3[threadIdx.x], s3[threadIdx.x + off]);
        }
        __syncthreads();
    }
    if (threadIdx.x == 0) {
        atomicAdd(&acc[0], s1[0]);
        atomicAdd(&acc[1], s2[0]);
        atomicMax((unsigned int*)&acc[2], __float_as_uint(s3[0]));
        __threadfence();
        unsigned int ticket = atomicAdd((unsigned int*)&acc[3], 1u);
        if (ticket == (unsigned int)(nblocks - 1)) {
            __threadfence();
            float a0 = atomicAdd(&acc[0], 0.0f);
            float a1 = atomicAdd(&acc[1], 0.0f);
            unsigned int mb = atomicOr((unsigned int*)&acc[2], 0u);
            out[0] = a0 + a1 * (REV_SCALEF / (__uint_as_float(mb) + EPSF));
        }
    }
}

extern "C" void kernel_launch(void* const* d_in, const int* in_sizes, int n_in,
                              void* d_out, int out_size, void* d_ws, size_t ws_size,
                              hipStream_t stream) {
    const float* overts = (const float*)d_in[0];
    const int*   ofaces = (const int*)d_in[1];
    const float* sverts = (const float*)d_in[2];
    const int*   sfaces = (const int*)d_in[3];
    const float* fp     = (const float*)d_in[4];
    const float* u1     = (const float*)d_in[5];
    const float* u2     = (const float*)d_in[6];
    float* out = (float*)d_out;

    const int N_ORIG = in_sizes[0] / 3;
    const int F_ORIG = in_sizes[1] / 3;
    const int F_SIMP = in_sizes[3] / 3;
    const int S      = in_sizes[5] / F_SIMP;
    const int NPTS   = F_SIMP * S;

    // tile counts (16 points/sources per tile)
    const int revPt = (NPTS + 15) / 16;      // 2000
    const int fwdPt = (F_SIMP + 15) / 16;    // 250
    const int revSt = (N_ORIG + 15) / 16;    // 500
    const int fwdSt = (F_ORIG + 15) / 16;    // 1000

    // workspace: revA | fwdA | revB | fwdB | rev_min | fwd_min | acc
    uint4* revA = (uint4*)d_ws;
    uint4* fwdA = revA + (size_t)revPt * 32;
    uint4* revB = fwdA + (size_t)fwdPt * 32;
    uint4* fwdB = revB + (size_t)revSt * 32;
    unsigned* rev_min = (unsigned*)(fwdB + (size_t)fwdSt * 32);
    unsigned* fwd_min = rev_min + NPTS;
    float* acc = (float*)(fwd_min + F_SIMP);

    // ---- prep ----
    int prepThreads = (revPt + fwdPt + revSt + fwdSt) * 32 + NPTS;
    hipLaunchKernelGGL(prep_kernel, dim3((prepThreads + 255) / 256), dim3(256), 0, stream,
                       overts, ofaces, sverts, sfaces, u1, u2,
                       revA, fwdA, revB, fwdB, rev_min, fwd_min, acc,
                       N_ORIG, F_ORIG, F_SIMP, S, NPTS,
                       revPt, fwdPt, revSt, fwdSt);

    // ---- mfma min ----
    // rev: 500 groups x 8 chunks (63 stiles) = 4000 waves
    // fwd: 63 groups x 16 chunks (63 stiles) = 1008 waves
    const int revGroups = (revPt + PTW - 1) / PTW;
    const int revChunks = 8;
    const int revCS = (revSt + revChunks - 1) / revChunks;
    const int revWaves = revGroups * revChunks;

    const int fwdGroups = (fwdPt + PTW - 1) / PTW;
    const int fwdChunks = 16;
    const int fwdCS = (fwdSt + fwdChunks - 1) / fwdChunks;
    const int fwdWaves = fwdGroups * fwdChunks;

    const int totalWaves = revWaves + fwdWaves;
    const int mblocks = (totalWaves + WPB - 1) / WPB;
    hipLaunchKernelGGL(mfma_min_kernel, dim3(mblocks), dim3(256), 0, stream,
                       revA, fwdA, revB, fwdB, rev_min, fwd_min,
                       revGroups, revWaves, revPt, NPTS, revSt, revCS,
                       fwdGroups, fwdPt, F_SIMP, fwdSt, fwdCS,
                       totalWaves);

    // ---- finalize ----
    const int finBlocks = (NPTS + FBLK - 1) / FBLK;
    hipLaunchKernelGGL(finalize_kernel, dim3(finBlocks), dim3(FBLK), 0, stream,
                       fwd_min, rev_min, fp, acc, out, F_SIMP, NPTS, S, finBlocks);
}